// Round 4
// baseline (524.183 us; speedup 1.0000x reference)
//
#include <hip/hip_runtime.h>
#include <math.h>

// NsNet2-style fused net on MI355X (gfx950).
// Activations batch-major [B,F] fp16; layers are C[B,M] = A[B,K] @ W[M,K]^T
// via mfma_f32_16x16x32_f16 (fp32 accum). Pads: 257->320, 400->448, 600->640.
// R3 counters: gemm_gru_h 50us @ MfmaUtil 15%, 6.25M LDS bank conflicts,
// serialized staging. R4 fixes:
//  - XOR-swizzled LDS (linear gload_lds dest + pre-swizzled GLOBAL chunk
//    (l&7)^(l>>3), swizzled reads) -> conflict-free ds_read_b128 (T2, rule #21)
//  - 2-phase prefetch: stage(t+1) -> compute(t) -> one barrier/K-step (T3 min)
//  - GRU fused into ONE kernel via K-concat [x;h], 4 acc groups (z,r,n_x,n_h)
//    since r multiplies only the h-side of n. Gi buffer eliminated (-88MB/layer).

#define B_TOTAL 16384
#define H16_TOTAL 3452928L   // fp16 weight elements
#define PREP_TOTAL 3460352L  // + 7424 bias floats

typedef _Float16 h8 __attribute__((ext_vector_type(8)));
typedef float f4 __attribute__((ext_vector_type(4)));

#define GLL(g, l) __builtin_amdgcn_global_load_lds(                         \
    (const __attribute__((address_space(1))) void*)(g),                     \
    (__attribute__((address_space(3))) void*)(l), 16, 0, 0)

// swizzled 16B-granule index for row-major [rows][64 fp16] LDS tiles
__device__ inline int swzg(int row, int c) { return row * 8 + (c ^ (row & 7)); }

// XCD-aware swizzle: grid = 128*NMT, NMT in {5,7,10,21} -> divisible by 8.
__device__ inline void swz_bt_mt(int bid, int& bt, int& mt) {
  const int xcd = bid & 7;
  const int i = bid >> 3;
  bt = xcd * 16 + (i & 15);
  mt = i >> 4;
}

// ---------------- weight/bias prep tables ----------------
__constant__ int kJsrc[32] = {3, 5,6,7, 8,9,10, 17,18,19, 20,21,22, 29, 31, 33,
                              4, 11,12,13, 14,15,16, 23,24,25, 26,27,28, 30, 32, 34};
__constant__ int kJM[32]   = {400, 400,400,400, 400,400,400, 400,400,400, 400,400,400, 600, 600, 257,
                              400, 400,400,400, 400,400,400, 400,400,400, 400,400,400, 600, 600, 257};
__constant__ int kJK[32]   = {257, 400,400,400, 400,400,400, 400,400,400, 400,400,400, 400, 600, 600,
                              1,1,1,1, 1,1,1, 1,1,1, 1,1,1, 1, 1, 1};
__constant__ int kJKp[32]  = {320, 448,448,448, 448,448,448, 448,448,448, 448,448,448, 448, 640, 640,
                              1,1,1,1, 1,1,1, 1,1,1, 1,1,1, 1, 1, 1};
__constant__ long kJcum[33] = {0,143360,344064,544768,745472,946176,1146880,1347584,1548288,1748992,
  1949696,2150400,2351104,2551808,2838528,3248128,3452928,3453376,3453824,3454272,3454720,3455168,
  3455616,3456064,3456512,3456960,3457408,3457856,3458304,3458752,3459392,3460032,3460352};

struct SrcPtrs { const float* p[35]; };

__global__ __launch_bounds__(256) void prep_weights(SrcPtrs sp, _Float16* __restrict__ w16,
                                                    float* __restrict__ b32) {
  long w = (long)blockIdx.x * 256 + threadIdx.x;
  if (w >= PREP_TOTAL) return;
  int j = 0;
  #pragma unroll 1
  while (j < 31 && kJcum[j + 1] <= w) j++;
  long local = w - kJcum[j];
  int Kp = kJKp[j];
  int m = (int)(local / Kp);
  int k = (int)(local - (long)m * Kp);
  float v = 0.f;
  if (m < kJM[j] && k < kJK[j]) v = sp.p[kJsrc[j]][(long)m * kJK[j] + k];
  if (j < 16) w16[w] = (_Float16)v;
  else        b32[w - H16_TOTAL] = v;
}

// ---------------- transposes ----------------
__global__ __launch_bounds__(256) void transpose_f32_to_h16(const float* __restrict__ src,
                                                            _Float16* __restrict__ dst,
                                                            int F, int Fp) {
  __shared__ float t[32][33];
  const int nFT = Fp >> 5;
  const int ft = blockIdx.x % nFT;
  const int bt = blockIdx.x / nFT;
  const int ci = threadIdx.x & 31, ri = threadIdx.x >> 5;
  #pragma unroll
  for (int p = 0; p < 4; ++p) {
    int f = ft * 32 + ri + p * 8;
    float v = (f < F) ? src[(long)f * B_TOTAL + bt * 32 + ci] : 0.f;
    t[ri + p * 8][ci] = v;
  }
  __syncthreads();
  #pragma unroll
  for (int p = 0; p < 4; ++p) {
    int b = bt * 32 + ri + p * 8;
    dst[(long)b * Fp + ft * 32 + ci] = (_Float16)t[ci][ri + p * 8];
  }
}

__global__ __launch_bounds__(256) void transpose_out(const float* __restrict__ src,
                                                     float* __restrict__ dst) {
  __shared__ float t[32][33];
  const int nFT = 10;
  const int ft = blockIdx.x % nFT;
  const int bt = blockIdx.x / nFT;
  const int ci = threadIdx.x & 31, ri = threadIdx.x >> 5;
  #pragma unroll
  for (int p = 0; p < 4; ++p)
    t[ri + p * 8][ci] = src[(long)(bt * 32 + ri + p * 8) * 320 + ft * 32 + ci];
  __syncthreads();
  #pragma unroll
  for (int p = 0; p < 4; ++p) {
    int f = ft * 32 + ri + p * 8;
    if (f < 257) dst[(long)f * B_TOTAL + bt * 32 + ci] = t[ci][ri + p * 8];
  }
}

// ---------------- GEMM: C[B,M] = A[B,K] @ W[M,K]^T (+bias, act) ----------------
// 128x64 tile, BK=64, 4 waves, double-buffered LDS, 2-phase prefetch,
// swizzled granules. ACT: 0 none, 1 relu, 2 sigmoid. OUTF32: fp32 C.
template <int ACT, int OUTF32>
__global__ __launch_bounds__(256) void gemm_tn(const _Float16* __restrict__ A,
                                               const _Float16* __restrict__ W,
                                               const float* __restrict__ bias,
                                               void* __restrict__ C, int K, int M) {
  __shared__ __align__(16) _Float16 As2[2][128 * 64];
  __shared__ __align__(16) _Float16 Ws2[2][64 * 64];
  const int tid = threadIdx.x;
  const int l = tid & 63;
  const int w = tid >> 6;
  int bt, mt;
  swz_bt_mt(blockIdx.x, bt, mt);
  const int wr = w >> 1, wc = w & 1;
  const int sc = ((l & 7) ^ (l >> 3)) * 8;  // pre-swizzled source chunk (elems)

  const _Float16* ag = A + (long)(bt * 128 + w * 32 + (l >> 3)) * K + sc;
  const _Float16* wg = W + (long)(mt * 64 + w * 16 + (l >> 3)) * K + sc;

  f4 acc[4][2];
  #pragma unroll
  for (int i = 0; i < 4; ++i)
    #pragma unroll
    for (int jj = 0; jj < 2; ++jj) acc[i][jj] = (f4){0.f, 0.f, 0.f, 0.f};

  const int lg = l >> 4;
  const int arow = wr * 64 + (l & 15);
  const int wrow = wc * 32 + (l & 15);
  const int KT = K >> 6;

  auto stage = [&](int b, int kt) {
    const _Float16* s = ag + kt * 64;
    char* ab = (char*)(As2[b]) + w * 4096;
    #pragma unroll
    for (int i = 0; i < 4; ++i) GLL(s + (long)i * 8 * K, ab + i * 1024);
    const _Float16* s2 = wg + kt * 64;
    char* wb = (char*)(Ws2[b]) + w * 2048;
    #pragma unroll
    for (int i = 0; i < 2; ++i) GLL(s2 + (long)i * 8 * K, wb + i * 1024);
  };

  stage(0, 0);
  __syncthreads();
  int cur = 0;
  for (int t = 0; t < KT; ++t) {
    if (t + 1 < KT) stage(cur ^ 1, t + 1);
    const h8* AsV = (const h8*)(As2[cur]);
    const h8* WsV = (const h8*)(Ws2[cur]);
    h8 bfr[2][2];
    #pragma unroll
    for (int fn = 0; fn < 2; ++fn) {
      bfr[fn][0] = WsV[swzg(wrow + fn * 16, lg)];
      bfr[fn][1] = WsV[swzg(wrow + fn * 16, 4 | lg)];
    }
    #pragma unroll
    for (int fm = 0; fm < 4; ++fm) {
      h8 a0 = AsV[swzg(arow + fm * 16, lg)];
      h8 a1 = AsV[swzg(arow + fm * 16, 4 | lg)];
      #pragma unroll
      for (int fn = 0; fn < 2; ++fn) {
        acc[fm][fn] = __builtin_amdgcn_mfma_f32_16x16x32_f16(a0, bfr[fn][0], acc[fm][fn], 0, 0, 0);
        acc[fm][fn] = __builtin_amdgcn_mfma_f32_16x16x32_f16(a1, bfr[fn][1], acc[fm][fn], 0, 0, 0);
      }
    }
    __syncthreads();
    cur ^= 1;
  }

  // epilogue; C/D frag: col=l&15, row=(l>>4)*4+reg
  const int colBase = mt * 64 + wc * 32 + (l & 15);
  const int rowBase = bt * 128 + wr * 64 + (l >> 4) * 4;
  #pragma unroll
  for (int fn = 0; fn < 2; ++fn) {
    const float bb = bias[colBase + fn * 16];
    #pragma unroll
    for (int fm = 0; fm < 4; ++fm) {
      #pragma unroll
      for (int r = 0; r < 4; ++r) {
        float x = acc[fm][fn][r] + bb;
        if (ACT == 1) x = fmaxf(x, 0.f);
        if (ACT == 2) x = 1.f / (1.f + __expf(-x));
        const long off = (long)(rowBase + fm * 16 + r) * M + colBase + fn * 16;
        if (OUTF32) ((float*)C)[off] = x;
        else        ((_Float16*)C)[off] = (_Float16)x;
      }
    }
  }
}

// ---------------- fully-fused GRU layer ----------------
// gates = Wi@[x] + Wh@[h] via K-concat (K=896, kt<7 -> x/Wi, kt>=7 -> h/Wh).
// acc groups: 0=z, 1=r, 2=n_x (Win@x), 3=n_h (Whn@h) since n = tanh(nx+bin
// + r*(nh+bhn)). h_old read from last-staged A-tile (rotation ends at h-tile mt).
#define GRU_MFMA(NIDX)                                                         \
  {                                                                            \
    h8 bfr[3][2][2];                                                           \
    _Pragma("unroll") for (int g = 0; g < 3; ++g)                              \
      _Pragma("unroll") for (int fn = 0; fn < 2; ++fn) {                       \
        bfr[g][fn][0] = WsV[g * 512 + swzg(wrow + fn * 16, lg)];               \
        bfr[g][fn][1] = WsV[g * 512 + swzg(wrow + fn * 16, 4 | lg)];           \
      }                                                                        \
    _Pragma("unroll") for (int fm = 0; fm < 4; ++fm) {                         \
      h8 a0 = AsV[swzg(arow + fm * 16, lg)];                                   \
      h8 a1 = AsV[swzg(arow + fm * 16, 4 | lg)];                               \
      _Pragma("unroll") for (int fn = 0; fn < 2; ++fn) {                       \
        acc[0][fm][fn] = __builtin_amdgcn_mfma_f32_16x16x32_f16(a0, bfr[0][fn][0], acc[0][fm][fn], 0, 0, 0); \
        acc[0][fm][fn] = __builtin_amdgcn_mfma_f32_16x16x32_f16(a1, bfr[0][fn][1], acc[0][fm][fn], 0, 0, 0); \
        acc[1][fm][fn] = __builtin_amdgcn_mfma_f32_16x16x32_f16(a0, bfr[1][fn][0], acc[1][fm][fn], 0, 0, 0); \
        acc[1][fm][fn] = __builtin_amdgcn_mfma_f32_16x16x32_f16(a1, bfr[1][fn][1], acc[1][fm][fn], 0, 0, 0); \
        acc[NIDX][fm][fn] = __builtin_amdgcn_mfma_f32_16x16x32_f16(a0, bfr[2][fn][0], acc[NIDX][fm][fn], 0, 0, 0); \
        acc[NIDX][fm][fn] = __builtin_amdgcn_mfma_f32_16x16x32_f16(a1, bfr[2][fn][1], acc[NIDX][fm][fn], 0, 0, 0); \
      }                                                                        \
    }                                                                          \
  }

__global__ __launch_bounds__(256, 2) void gemm_gru(const _Float16* __restrict__ Ax,
                                                   const _Float16* __restrict__ Ah,
                                                   const _Float16* __restrict__ Wi_,
                                                   const _Float16* __restrict__ Wh_,
                                                   const float* __restrict__ bi,
                                                   const float* __restrict__ bh,
                                                   _Float16* __restrict__ Hn) {
  __shared__ __align__(16) _Float16 As2[2][128 * 64];
  __shared__ __align__(16) _Float16 Ws2[2][3][64 * 64];
  const int tid = threadIdx.x;
  const int l = tid & 63;
  const int w = tid >> 6;
  int bt, mt;
  swz_bt_mt(blockIdx.x, bt, mt);  // mt in [0,7)
  const int wr = w >> 1, wc = w & 1;
  const int sc = ((l & 7) ^ (l >> 3)) * 8;

  const long arowg = (long)(bt * 128 + w * 32 + (l >> 3)) * 448 + sc;
  const long wrowg = (long)(mt * 64 + w * 16 + (l >> 3)) * 448 + sc;

  f4 acc[4][4][2];
  #pragma unroll
  for (int g = 0; g < 4; ++g)
    #pragma unroll
    for (int i = 0; i < 4; ++i)
      #pragma unroll
      for (int jj = 0; jj < 2; ++jj) acc[g][i][jj] = (f4){0.f, 0.f, 0.f, 0.f};

  const int lg = l >> 4;
  const int arow = wr * 64 + (l & 15);
  const int wrow = wc * 32 + (l & 15);

  auto stage = [&](int b, int kt) {
    const int kh = kt >= 7;
    const _Float16* As_ = kh ? Ah : Ax;
    const _Float16* Ws_ = kh ? Wh_ : Wi_;
    const int kc = (kt - (kh ? 7 : 0)) * 64;
    const _Float16* s = As_ + arowg + kc;
    char* ab = (char*)(As2[b]) + w * 4096;
    #pragma unroll
    for (int i = 0; i < 4; ++i) GLL(s + (long)i * 8 * 448, ab + i * 1024);
    const _Float16* s2 = Ws_ + wrowg + kc;
    char* wb = (char*)(Ws2[b]) + w * 2048;
    #pragma unroll
    for (int g = 0; g < 3; ++g) {
      GLL(s2 + (long)g * 200704, wb + g * 8192);
      GLL(s2 + (long)g * 200704 + 8 * 448, wb + g * 8192 + 1024);
    }
  };

  // rotation: kt(i) = (mt+8+i) % 14; last = mt+7 (the h-tile needed in epilogue)
  stage(0, (mt + 8) % 14);
  __syncthreads();
  int cur = 0;
  for (int i = 0; i < 14; ++i) {
    const int kt = (mt + 8 + i) % 14;
    if (i < 13) stage(cur ^ 1, (mt + 9 + i) % 14);
    const h8* AsV = (const h8*)(As2[cur]);
    const h8* WsV = (const h8*)(Ws2[cur][0]);
    if (kt < 7) GRU_MFMA(2) else GRU_MFMA(3)
    __syncthreads();
    if (i < 13) cur ^= 1;
  }

  // epilogue: gate math; h_old from As2[cur] (h-tile mt), swizzled scalar reads
  const _Float16* Alast = As2[cur];
  const int jloc = wc * 32 + (l & 15);
  const int rowLoc = wr * 64 + (l >> 4) * 4;
  const long rowGlob = (long)bt * 128 + rowLoc;
  #pragma unroll
  for (int fn = 0; fn < 2; ++fn) {
    const int j = mt * 64 + jloc + fn * 16;
    const float bz = bi[j] + bh[j];
    const float br = bi[448 + j] + bh[448 + j];
    const float bnx = bi[896 + j], bnh = bh[896 + j];
    #pragma unroll
    for (int fm = 0; fm < 4; ++fm) {
      #pragma unroll
      for (int r = 0; r < 4; ++r) {
        const float zz = 1.f / (1.f + __expf(-(acc[0][fm][fn][r] + bz)));
        const float rr = 1.f / (1.f + __expf(-(acc[1][fm][fn][r] + br)));
        const float nn = (acc[2][fm][fn][r] + bnx) + rr * (acc[3][fm][fn][r] + bnh);
        const float th = 1.f - 2.f / (__expf(2.f * nn) + 1.f);  // tanh
        const int row = rowLoc + fm * 16 + r;
        const int col = jloc + fn * 16;
        const float ho = (float)Alast[swzg(row, col >> 3) * 8 + (col & 7)];
        Hn[(rowGlob + fm * 16 + r) * 448 + j] = (_Float16)((1.f - zz) * th + zz * ho);
      }
    }
  }
}

// ---------------- launch ----------------
extern "C" void kernel_launch(void* const* d_in, const int* in_sizes, int n_in,
                              void* d_out, int out_size, void* d_ws, size_t ws_size,
                              hipStream_t stream) {
  char* ws = (char*)d_ws;
  _Float16* W16  = (_Float16*)(ws);                 // 3,452,928 fp16
  float*    BIAS = (float*)(ws + 6905856L);         // 7,424 f32
  _Float16* buf2 = (_Float16*)(ws + 6935552L);      // xT [B,320] -> y1 [B,640] -> outT f32 [B,320]
  _Float16* buf3 = (_Float16*)(ws + 27907072L);     // fc1out [B,448] -> y2 [B,640]
  _Float16* buf4 = (_Float16*)(ws + 48878592L);     // h1_old -> h2_new [B,448]
  _Float16* buf5 = (_Float16*)(ws + 63558656L);     // h2_old [B,448]
  _Float16* buf6 = (_Float16*)(ws + 78238720L);     // h1_new [B,448]
  float* outT = (float*)buf2;                       // [B,320] f32 (y1 dead by fc4)
  if (ws_size < 92918784UL) return;  // loud failure rather than OOB

  SrcPtrs sp;
  for (int i = 0; i < 35; ++i) sp.p[i] = (const float*)d_in[i];

  prep_weights<<<dim3(13517), dim3(256), 0, stream>>>(sp, W16, BIAS);
  transpose_f32_to_h16<<<dim3(10 * 512), dim3(256), 0, stream>>>((const float*)d_in[0], buf2, 257, 320);
  transpose_f32_to_h16<<<dim3(14 * 512), dim3(256), 0, stream>>>((const float*)d_in[1], buf4, 400, 448);
  transpose_f32_to_h16<<<dim3(14 * 512), dim3(256), 0, stream>>>((const float*)d_in[2], buf5, 400, 448);

  // fc1: [B,320] @ [448,320]^T -> [B,448]
  gemm_tn<0, 0><<<dim3(128 * 7), dim3(256), 0, stream>>>(buf2, W16, BIAS, (void*)buf3, 320, 448);
  // GRU1 (fused): gates from [fc1out ; h1_old], writes h1_new
  gemm_gru<<<dim3(128 * 7), dim3(256), 0, stream>>>(buf3, buf4, W16 + 143360, W16 + 745472,
                                                    BIAS + 448, BIAS + 1792, buf6);
  // GRU2 (fused): gates from [h1_new ; h2_old], writes h2_new
  gemm_gru<<<dim3(128 * 7), dim3(256), 0, stream>>>(buf6, buf5, W16 + 1347584, W16 + 1949696,
                                                    BIAS + 3136, BIAS + 4480, buf4);
  // fc2 (relu), fc3 (relu), fc4 (sigmoid, fp32 out)
  gemm_tn<1, 0><<<dim3(128 * 10), dim3(256), 0, stream>>>(buf4, W16 + 2551808, BIAS + 5824, (void*)buf2, 448, 640);
  gemm_tn<1, 0><<<dim3(128 * 10), dim3(256), 0, stream>>>(buf2, W16 + 2838528, BIAS + 6464, (void*)buf3, 640, 640);
  gemm_tn<2, 1><<<dim3(128 * 5), dim3(256), 0, stream>>>(buf3, W16 + 3248128, BIAS + 7104, (void*)outT, 640, 320);

  transpose_out<<<dim3(10 * 512), dim3(256), 0, stream>>>(outT, (float*)d_out);
}

// Round 5
// 408.790 us; speedup vs baseline: 1.2823x; 1.2823x over previous
//
#include <hip/hip_runtime.h>
#include <math.h>

// NsNet2-style fused net on MI355X (gfx950).
// Activations batch-major [B,F] fp16; layers are C[B,M] = A[B,K] @ W[M,K]^T
// via mfma_f32_16x16x32_f16 (fp32 accum). Pads: 257->320, 400->448, 600->640.
// R4 post-mortem: gemm_gru spilled (4 acc groups = 290 regs > 256 cap ->
// 157MB scratch writes). R5: 3 acc groups via K-phase ordering -- x-tiles
// first (z,r,nx), park nx as fp16 (+bin) at boundary, reuse acc[2] for nh
// over h-tiles (ending at tile mt so h_old stays in LDS for the blend).
// LDS swizzle kept (conflicts 6.25M -> 0 in R4), 2-phase prefetch kept.

#define B_TOTAL 16384
#define H16_TOTAL 3452928L   // fp16 weight elements
#define PREP_TOTAL 3460352L  // + 7424 bias floats

typedef _Float16 h8 __attribute__((ext_vector_type(8)));
typedef _Float16 h4 __attribute__((ext_vector_type(4)));
typedef float f4 __attribute__((ext_vector_type(4)));

#define GLL(g, l) __builtin_amdgcn_global_load_lds(                         \
    (const __attribute__((address_space(1))) void*)(g),                     \
    (__attribute__((address_space(3))) void*)(l), 16, 0, 0)

// swizzled 16B-granule index for row-major [rows][64 fp16] LDS tiles
__device__ inline int swzg(int row, int c) { return row * 8 + (c ^ (row & 7)); }

// XCD-aware swizzle: grid = 128*NMT, NMT in {5,7,10,21} -> divisible by 8.
__device__ inline void swz_bt_mt(int bid, int& bt, int& mt) {
  const int xcd = bid & 7;
  const int i = bid >> 3;
  bt = xcd * 16 + (i & 15);
  mt = i >> 4;
}

// ---------------- weight/bias prep tables ----------------
__constant__ int kJsrc[32] = {3, 5,6,7, 8,9,10, 17,18,19, 20,21,22, 29, 31, 33,
                              4, 11,12,13, 14,15,16, 23,24,25, 26,27,28, 30, 32, 34};
__constant__ int kJM[32]   = {400, 400,400,400, 400,400,400, 400,400,400, 400,400,400, 600, 600, 257,
                              400, 400,400,400, 400,400,400, 400,400,400, 400,400,400, 600, 600, 257};
__constant__ int kJK[32]   = {257, 400,400,400, 400,400,400, 400,400,400, 400,400,400, 400, 600, 600,
                              1,1,1,1, 1,1,1, 1,1,1, 1,1,1, 1, 1, 1};
__constant__ int kJKp[32]  = {320, 448,448,448, 448,448,448, 448,448,448, 448,448,448, 448, 640, 640,
                              1,1,1,1, 1,1,1, 1,1,1, 1,1,1, 1, 1, 1};
__constant__ long kJcum[33] = {0,143360,344064,544768,745472,946176,1146880,1347584,1548288,1748992,
  1949696,2150400,2351104,2551808,2838528,3248128,3452928,3453376,3453824,3454272,3454720,3455168,
  3455616,3456064,3456512,3456960,3457408,3457856,3458304,3458752,3459392,3460032,3460352};

struct SrcPtrs { const float* p[35]; };

__global__ __launch_bounds__(256) void prep_weights(SrcPtrs sp, _Float16* __restrict__ w16,
                                                    float* __restrict__ b32) {
  long w = (long)blockIdx.x * 256 + threadIdx.x;
  if (w >= PREP_TOTAL) return;
  int j = 0;
  #pragma unroll 1
  while (j < 31 && kJcum[j + 1] <= w) j++;
  long local = w - kJcum[j];
  int Kp = kJKp[j];
  int m = (int)(local / Kp);
  int k = (int)(local - (long)m * Kp);
  float v = 0.f;
  if (m < kJM[j] && k < kJK[j]) v = sp.p[kJsrc[j]][(long)m * kJK[j] + k];
  if (j < 16) w16[w] = (_Float16)v;
  else        b32[w - H16_TOTAL] = v;
}

// ---------------- input transposes (one launch for x, h1, h2) ----------------
// src [F, 16384] f32 -> dst [16384, Fp] fp16, zero pad f>=F.
__global__ __launch_bounds__(256) void transpose_in(const float* __restrict__ x,
                                                    const float* __restrict__ h1,
                                                    const float* __restrict__ h2,
                                                    _Float16* __restrict__ dx,
                                                    _Float16* __restrict__ dh1,
                                                    _Float16* __restrict__ dh2) {
  __shared__ float t[32][33];
  int b = blockIdx.x;
  const float* src; _Float16* dst; int F, nFT;
  if (b < 5120)        { src = x;  dst = dx;  F = 257; nFT = 10; }
  else if (b < 12288)  { b -= 5120;  src = h1; dst = dh1; F = 400; nFT = 14; }
  else                 { b -= 12288; src = h2; dst = dh2; F = 400; nFT = 14; }
  const int Fp = nFT * 32;
  const int ft = b % nFT;
  const int bt = b / nFT;
  const int ci = threadIdx.x & 31, ri = threadIdx.x >> 5;
  #pragma unroll
  for (int p = 0; p < 4; ++p) {
    int f = ft * 32 + ri + p * 8;
    float v = (f < F) ? src[(long)f * B_TOTAL + bt * 32 + ci] : 0.f;
    t[ri + p * 8][ci] = v;
  }
  __syncthreads();
  #pragma unroll
  for (int p = 0; p < 4; ++p) {
    int bb = bt * 32 + ri + p * 8;
    dst[(long)bb * Fp + ft * 32 + ci] = (_Float16)t[ci][ri + p * 8];
  }
}

__global__ __launch_bounds__(256) void transpose_out(const float* __restrict__ src,
                                                     float* __restrict__ dst) {
  __shared__ float t[32][33];
  const int nFT = 10;
  const int ft = blockIdx.x % nFT;
  const int bt = blockIdx.x / nFT;
  const int ci = threadIdx.x & 31, ri = threadIdx.x >> 5;
  #pragma unroll
  for (int p = 0; p < 4; ++p)
    t[ri + p * 8][ci] = src[(long)(bt * 32 + ri + p * 8) * 320 + ft * 32 + ci];
  __syncthreads();
  #pragma unroll
  for (int p = 0; p < 4; ++p) {
    int f = ft * 32 + ri + p * 8;
    if (f < 257) dst[(long)f * B_TOTAL + bt * 32 + ci] = t[ci][ri + p * 8];
  }
}

// ---------------- GEMM: C[B,M] = A[B,K] @ W[M,K]^T (+bias, act) ----------------
// 128x64 tile, BK=64, 4 waves, double-buffered LDS, 2-phase prefetch,
// swizzled granules. ACT: 0 none, 1 relu, 2 sigmoid. OUTF32: fp32 C.
template <int ACT, int OUTF32>
__global__ __launch_bounds__(256) void gemm_tn(const _Float16* __restrict__ A,
                                               const _Float16* __restrict__ W,
                                               const float* __restrict__ bias,
                                               void* __restrict__ C, int K, int M) {
  __shared__ __align__(16) _Float16 As2[2][128 * 64];
  __shared__ __align__(16) _Float16 Ws2[2][64 * 64];
  const int tid = threadIdx.x;
  const int l = tid & 63;
  const int w = tid >> 6;
  int bt, mt;
  swz_bt_mt(blockIdx.x, bt, mt);
  const int wr = w >> 1, wc = w & 1;
  const int sc = ((l & 7) ^ (l >> 3)) * 8;  // pre-swizzled source chunk (elems)

  const _Float16* ag = A + (long)(bt * 128 + w * 32 + (l >> 3)) * K + sc;
  const _Float16* wg = W + (long)(mt * 64 + w * 16 + (l >> 3)) * K + sc;

  f4 acc[4][2];
  #pragma unroll
  for (int i = 0; i < 4; ++i)
    #pragma unroll
    for (int jj = 0; jj < 2; ++jj) acc[i][jj] = (f4){0.f, 0.f, 0.f, 0.f};

  const int lg = l >> 4;
  const int arow = wr * 64 + (l & 15);
  const int wrow = wc * 32 + (l & 15);
  const int KT = K >> 6;

  auto stage = [&](int b, int kt) {
    const _Float16* s = ag + kt * 64;
    char* ab = (char*)(As2[b]) + w * 4096;
    #pragma unroll
    for (int i = 0; i < 4; ++i) GLL(s + (long)i * 8 * K, ab + i * 1024);
    const _Float16* s2 = wg + kt * 64;
    char* wb = (char*)(Ws2[b]) + w * 2048;
    #pragma unroll
    for (int i = 0; i < 2; ++i) GLL(s2 + (long)i * 8 * K, wb + i * 1024);
  };

  stage(0, 0);
  __syncthreads();
  int cur = 0;
  for (int t = 0; t < KT; ++t) {
    if (t + 1 < KT) stage(cur ^ 1, t + 1);
    const h8* AsV = (const h8*)(As2[cur]);
    const h8* WsV = (const h8*)(Ws2[cur]);
    h8 bfr[2][2];
    #pragma unroll
    for (int fn = 0; fn < 2; ++fn) {
      bfr[fn][0] = WsV[swzg(wrow + fn * 16, lg)];
      bfr[fn][1] = WsV[swzg(wrow + fn * 16, 4 | lg)];
    }
    #pragma unroll
    for (int fm = 0; fm < 4; ++fm) {
      h8 a0 = AsV[swzg(arow + fm * 16, lg)];
      h8 a1 = AsV[swzg(arow + fm * 16, 4 | lg)];
      #pragma unroll
      for (int fn = 0; fn < 2; ++fn) {
        acc[fm][fn] = __builtin_amdgcn_mfma_f32_16x16x32_f16(a0, bfr[fn][0], acc[fm][fn], 0, 0, 0);
        acc[fm][fn] = __builtin_amdgcn_mfma_f32_16x16x32_f16(a1, bfr[fn][1], acc[fm][fn], 0, 0, 0);
      }
    }
    __syncthreads();
    cur ^= 1;
  }

  // epilogue; C/D frag: col=l&15, row=(l>>4)*4+reg
  const int colBase = mt * 64 + wc * 32 + (l & 15);
  const int rowBase = bt * 128 + wr * 64 + (l >> 4) * 4;
  #pragma unroll
  for (int fn = 0; fn < 2; ++fn) {
    const float bb = bias[colBase + fn * 16];
    #pragma unroll
    for (int fm = 0; fm < 4; ++fm) {
      #pragma unroll
      for (int r = 0; r < 4; ++r) {
        float x = acc[fm][fn][r] + bb;
        if (ACT == 1) x = fmaxf(x, 0.f);
        if (ACT == 2) x = 1.f / (1.f + __expf(-x));
        const long off = (long)(rowBase + fm * 16 + r) * M + colBase + fn * 16;
        if (OUTF32) ((float*)C)[off] = x;
        else        ((_Float16*)C)[off] = (_Float16)x;
      }
    }
  }
}

// ---------------- fully-fused GRU layer (3 acc groups + nx parking) ----------------
// gates = Wi@[x] + Wh@[h] via K-concat (K=896). K-order: x-tiles 0..6 first
// (acc = z,r,nx), park nx+bin as fp16, zero acc[2]; then h-tiles rotated to end
// at tile mt (acc[2] = nh; h_old in last LDS A-tile for the blend).
__global__ __launch_bounds__(256) void gemm_gru(const _Float16* __restrict__ Ax,
                                                const _Float16* __restrict__ Ah,
                                                const _Float16* __restrict__ Wi_,
                                                const _Float16* __restrict__ Wh_,
                                                const float* __restrict__ bi,
                                                const float* __restrict__ bh,
                                                _Float16* __restrict__ Hn) {
  __shared__ __align__(16) _Float16 As2[2][128 * 64];
  __shared__ __align__(16) _Float16 Ws2[2][3][64 * 64];
  const int tid = threadIdx.x;
  const int l = tid & 63;
  const int w = tid >> 6;
  int bt, mt;
  swz_bt_mt(blockIdx.x, bt, mt);  // mt in [0,7)
  const int wr = w >> 1, wc = w & 1;
  const int sc = ((l & 7) ^ (l >> 3)) * 8;

  const long arowg = (long)(bt * 128 + w * 32 + (l >> 3)) * 448 + sc;
  const long wrowg = (long)(mt * 64 + w * 16 + (l >> 3)) * 448 + sc;

  f4 acc[3][4][2];
  #pragma unroll
  for (int g = 0; g < 3; ++g)
    #pragma unroll
    for (int i = 0; i < 4; ++i)
      #pragma unroll
      for (int jj = 0; jj < 2; ++jj) acc[g][i][jj] = (f4){0.f, 0.f, 0.f, 0.f};
  h4 nxp[4][2];  // parked nx (+bin) in fp16

  const int lg = l >> 4;
  const int arow = wr * 64 + (l & 15);
  const int wrow = wc * 32 + (l & 15);
  const int colBase = mt * 64 + wc * 32 + (l & 15);
  const float bnx0 = bi[896 + colBase], bnx1 = bi[896 + colBase + 16];

  auto stage = [&](int b, int kt) {
    const int kh = kt >= 7;
    const _Float16* As_ = kh ? Ah : Ax;
    const _Float16* Ws_ = kh ? Wh_ : Wi_;
    const int kc = (kt - (kh ? 7 : 0)) * 64;
    const _Float16* s = As_ + arowg + kc;
    char* ab = (char*)(As2[b]) + w * 4096;
    #pragma unroll
    for (int i = 0; i < 4; ++i) GLL(s + (long)i * 8 * 448, ab + i * 1024);
    const _Float16* s2 = Ws_ + wrowg + kc;
    char* wb = (char*)(Ws2[b]) + w * 2048;
    #pragma unroll
    for (int g = 0; g < 3; ++g) {
      GLL(s2 + (long)g * 200704, wb + g * 8192);
      GLL(s2 + (long)g * 200704 + 8 * 448, wb + g * 8192 + 1024);
    }
  };

  // K-order: i<7 -> x-tile i; i>=7 -> h-tile 7 + ((mt+i-6)%7); last = 7+mt.
  auto ktOf = [&](int i) { return i < 7 ? i : 7 + ((mt + i - 6) % 7); };

  stage(0, 0);
  __syncthreads();
  int cur = 0;
  for (int i = 0; i < 14; ++i) {
    if (i < 13) stage(cur ^ 1, ktOf(i + 1));
    const h8* AsV = (const h8*)(As2[cur]);
    const h8* WsV = (const h8*)(Ws2[cur][0]);
    h8 a[4][2];
    #pragma unroll
    for (int fm = 0; fm < 4; ++fm) {
      a[fm][0] = AsV[swzg(arow + fm * 16, lg)];
      a[fm][1] = AsV[swzg(arow + fm * 16, 4 | lg)];
    }
    #pragma unroll
    for (int g = 0; g < 3; ++g) {
      h8 b00 = WsV[g * 512 + swzg(wrow, lg)];
      h8 b01 = WsV[g * 512 + swzg(wrow, 4 | lg)];
      h8 b10 = WsV[g * 512 + swzg(wrow + 16, lg)];
      h8 b11 = WsV[g * 512 + swzg(wrow + 16, 4 | lg)];
      #pragma unroll
      for (int fm = 0; fm < 4; ++fm) {
        acc[g][fm][0] = __builtin_amdgcn_mfma_f32_16x16x32_f16(a[fm][0], b00, acc[g][fm][0], 0, 0, 0);
        acc[g][fm][0] = __builtin_amdgcn_mfma_f32_16x16x32_f16(a[fm][1], b01, acc[g][fm][0], 0, 0, 0);
        acc[g][fm][1] = __builtin_amdgcn_mfma_f32_16x16x32_f16(a[fm][0], b10, acc[g][fm][1], 0, 0, 0);
        acc[g][fm][1] = __builtin_amdgcn_mfma_f32_16x16x32_f16(a[fm][1], b11, acc[g][fm][1], 0, 0, 0);
      }
    }
    if (i == 6) {  // x-phase done: park nx (+bin) as fp16, reuse acc[2] for nh
      #pragma unroll
      for (int fm = 0; fm < 4; ++fm)
        #pragma unroll
        for (int fn = 0; fn < 2; ++fn) {
          const float bb = fn ? bnx1 : bnx0;
          #pragma unroll
          for (int r = 0; r < 4; ++r) nxp[fm][fn][r] = (_Float16)(acc[2][fm][fn][r] + bb);
          acc[2][fm][fn] = (f4){0.f, 0.f, 0.f, 0.f};
        }
    }
    __syncthreads();
    if (i < 13) cur ^= 1;
  }

  // epilogue: gate math; h_old from As2[cur] (h-tile mt), swizzled scalar reads
  const _Float16* Alast = As2[cur];
  const int jloc = wc * 32 + (l & 15);
  const int rowLoc = wr * 64 + (l >> 4) * 4;
  const long rowGlob = (long)bt * 128 + rowLoc;
  #pragma unroll
  for (int fn = 0; fn < 2; ++fn) {
    const int j = colBase + fn * 16;
    const float bz = bi[j] + bh[j];
    const float br = bi[448 + j] + bh[448 + j];
    const float bnh = bh[896 + j];
    #pragma unroll
    for (int fm = 0; fm < 4; ++fm) {
      #pragma unroll
      for (int r = 0; r < 4; ++r) {
        const float zz = 1.f / (1.f + __expf(-(acc[0][fm][fn][r] + bz)));
        const float rr = 1.f / (1.f + __expf(-(acc[1][fm][fn][r] + br)));
        const float nn = (float)nxp[fm][fn][r] + rr * (acc[2][fm][fn][r] + bnh);
        const float th = 1.f - 2.f / (__expf(2.f * nn) + 1.f);  // tanh
        const int row = rowLoc + fm * 16 + r;
        const int col = jloc + fn * 16;
        const float ho = (float)Alast[swzg(row, col >> 3) * 8 + (col & 7)];
        Hn[(rowGlob + fm * 16 + r) * 448 + j] = (_Float16)((1.f - zz) * th + zz * ho);
      }
    }
  }
}

// ---------------- launch ----------------
extern "C" void kernel_launch(void* const* d_in, const int* in_sizes, int n_in,
                              void* d_out, int out_size, void* d_ws, size_t ws_size,
                              hipStream_t stream) {
  char* ws = (char*)d_ws;
  _Float16* W16  = (_Float16*)(ws);                 // 3,452,928 fp16
  float*    BIAS = (float*)(ws + 6905856L);         // 7,424 f32
  _Float16* buf2 = (_Float16*)(ws + 6935552L);      // xT [B,320] -> y1 [B,640] -> outT f32 [B,320]
  _Float16* buf3 = (_Float16*)(ws + 27907072L);     // fc1out [B,448] -> y2 [B,640]
  _Float16* buf4 = (_Float16*)(ws + 48878592L);     // h1_old -> h2_new [B,448]
  _Float16* buf5 = (_Float16*)(ws + 63558656L);     // h2_old [B,448]
  _Float16* buf6 = (_Float16*)(ws + 78238720L);     // h1_new [B,448]
  float* outT = (float*)buf2;                       // [B,320] f32 (y1 dead by fc4)
  if (ws_size < 92918784UL) return;  // loud failure rather than OOB

  SrcPtrs sp;
  for (int i = 0; i < 35; ++i) sp.p[i] = (const float*)d_in[i];

  prep_weights<<<dim3(13517), dim3(256), 0, stream>>>(sp, W16, BIAS);
  transpose_in<<<dim3(19456), dim3(256), 0, stream>>>((const float*)d_in[0], (const float*)d_in[1],
                                                      (const float*)d_in[2], buf2, buf4, buf5);

  // fc1: [B,320] @ [448,320]^T -> [B,448]
  gemm_tn<0, 0><<<dim3(128 * 7), dim3(256), 0, stream>>>(buf2, W16, BIAS, (void*)buf3, 320, 448);
  // GRU1 (fused): gates from [fc1out ; h1_old], writes h1_new
  gemm_gru<<<dim3(128 * 7), dim3(256), 0, stream>>>(buf3, buf4, W16 + 143360, W16 + 745472,
                                                    BIAS + 448, BIAS + 1792, buf6);
  // GRU2 (fused): gates from [h1_new ; h2_old], writes h2_new
  gemm_gru<<<dim3(128 * 7), dim3(256), 0, stream>>>(buf6, buf5, W16 + 1347584, W16 + 1949696,
                                                    BIAS + 3136, BIAS + 4480, buf4);
  // fc2 (relu), fc3 (relu), fc4 (sigmoid, fp32 out)
  gemm_tn<1, 0><<<dim3(128 * 10), dim3(256), 0, stream>>>(buf4, W16 + 2551808, BIAS + 5824, (void*)buf2, 448, 640);
  gemm_tn<1, 0><<<dim3(128 * 10), dim3(256), 0, stream>>>(buf2, W16 + 2838528, BIAS + 6464, (void*)buf3, 640, 640);
  gemm_tn<2, 1><<<dim3(128 * 5), dim3(256), 0, stream>>>(buf3, W16 + 3248128, BIAS + 7104, (void*)outT, 640, 320);

  transpose_out<<<dim3(10 * 512), dim3(256), 0, stream>>>(outT, (float*)d_out);
}

// Round 6
// 394.992 us; speedup vs baseline: 1.3271x; 1.0349x over previous
//
#include <hip/hip_runtime.h>
#include <math.h>

// NsNet2-style fused net on MI355X (gfx950).
// Activations batch-major [B,F] fp16; layers are C[B,M] = A[B,K] @ W[M,K]^T
// via mfma_f32_16x16x32_f16 (fp32 accum). Pads: 257->320, 400->448, 600->640.
// R5 counters: gru 65us @ MfmaUtil 24%, VALUBusy 40%, Occ 17% (LDS-capped),
// spill gone. R6: (1) 512-thr blocks, wave=32x32 -> gru acc 96->64 VGPR,
// 16 waves/CU; (2) fully-unrolled K-loops (static LDS addrs, VALU down);
// (3) LDS-transpose epilogue -> dense 16B stores. Swizzle+dbuf+XCD kept.

#define B_TOTAL 16384
#define H16_TOTAL 3452928L   // fp16 weight elements
#define PREP_TOTAL 3460352L  // + 7424 bias floats

typedef _Float16 h8 __attribute__((ext_vector_type(8)));
typedef float f4 __attribute__((ext_vector_type(4)));

#define GLL(g, l) __builtin_amdgcn_global_load_lds(                         \
    (const __attribute__((address_space(1))) void*)(g),                     \
    (__attribute__((address_space(3))) void*)(l), 16, 0, 0)

#define MFMA(d, a_, b_) d = __builtin_amdgcn_mfma_f32_16x16x32_f16(a_, b_, d, 0, 0, 0)

// swizzled 16B-granule index for row-major [rows][64 fp16] LDS tiles
__device__ inline int swzg(int row, int c) { return row * 8 + (c ^ (row & 7)); }

// XCD-aware swizzle: grid = 128*NMT, NMT in {5,7,10} -> divisible by 8.
__device__ inline void swz_bt_mt(int bid, int& bt, int& mt) {
  const int xcd = bid & 7;
  const int i = bid >> 3;
  bt = xcd * 16 + (i & 15);
  mt = i >> 4;
}

// ---------------- weight/bias prep tables ----------------
__constant__ int kJsrc[32] = {3, 5,6,7, 8,9,10, 17,18,19, 20,21,22, 29, 31, 33,
                              4, 11,12,13, 14,15,16, 23,24,25, 26,27,28, 30, 32, 34};
__constant__ int kJM[32]   = {400, 400,400,400, 400,400,400, 400,400,400, 400,400,400, 600, 600, 257,
                              400, 400,400,400, 400,400,400, 400,400,400, 400,400,400, 600, 600, 257};
__constant__ int kJK[32]   = {257, 400,400,400, 400,400,400, 400,400,400, 400,400,400, 400, 600, 600,
                              1,1,1,1, 1,1,1, 1,1,1, 1,1,1, 1, 1, 1};
__constant__ int kJKp[32]  = {320, 448,448,448, 448,448,448, 448,448,448, 448,448,448, 448, 640, 640,
                              1,1,1,1, 1,1,1, 1,1,1, 1,1,1, 1, 1, 1};
__constant__ long kJcum[33] = {0,143360,344064,544768,745472,946176,1146880,1347584,1548288,1748992,
  1949696,2150400,2351104,2551808,2838528,3248128,3452928,3453376,3453824,3454272,3454720,3455168,
  3455616,3456064,3456512,3456960,3457408,3457856,3458304,3458752,3459392,3460032,3460352};

struct SrcPtrs { const float* p[35]; };

__global__ __launch_bounds__(256) void prep_weights(SrcPtrs sp, _Float16* __restrict__ w16,
                                                    float* __restrict__ b32) {
  long w = (long)blockIdx.x * 256 + threadIdx.x;
  if (w >= PREP_TOTAL) return;
  int j = 0;
  #pragma unroll 1
  while (j < 31 && kJcum[j + 1] <= w) j++;
  long local = w - kJcum[j];
  int Kp = kJKp[j];
  int m = (int)(local / Kp);
  int k = (int)(local - (long)m * Kp);
  float v = 0.f;
  if (m < kJM[j] && k < kJK[j]) v = sp.p[kJsrc[j]][(long)m * kJK[j] + k];
  if (j < 16) w16[w] = (_Float16)v;
  else        b32[w - H16_TOTAL] = v;
}

// ---------------- input transposes (one launch for x, h1, h2) ----------------
__global__ __launch_bounds__(256) void transpose_in(const float* __restrict__ x,
                                                    const float* __restrict__ h1,
                                                    const float* __restrict__ h2,
                                                    _Float16* __restrict__ dx,
                                                    _Float16* __restrict__ dh1,
                                                    _Float16* __restrict__ dh2) {
  __shared__ float t[32][33];
  int b = blockIdx.x;
  const float* src; _Float16* dst; int F, nFT;
  if (b < 5120)        { src = x;  dst = dx;  F = 257; nFT = 10; }
  else if (b < 12288)  { b -= 5120;  src = h1; dst = dh1; F = 400; nFT = 14; }
  else                 { b -= 12288; src = h2; dst = dh2; F = 400; nFT = 14; }
  const int Fp = nFT * 32;
  const int ft = b % nFT;
  const int bt = b / nFT;
  const int ci = threadIdx.x & 31, ri = threadIdx.x >> 5;
  #pragma unroll
  for (int p = 0; p < 4; ++p) {
    int f = ft * 32 + ri + p * 8;
    float v = (f < F) ? src[(long)f * B_TOTAL + bt * 32 + ci] : 0.f;
    t[ri + p * 8][ci] = v;
  }
  __syncthreads();
  #pragma unroll
  for (int p = 0; p < 4; ++p) {
    int bb = bt * 32 + ri + p * 8;
    dst[(long)bb * Fp + ft * 32 + ci] = (_Float16)t[ci][ri + p * 8];
  }
}

__global__ __launch_bounds__(256) void transpose_out(const float* __restrict__ src,
                                                     float* __restrict__ dst) {
  __shared__ float t[32][33];
  const int nFT = 10;
  const int ft = blockIdx.x % nFT;
  const int bt = blockIdx.x / nFT;
  const int ci = threadIdx.x & 31, ri = threadIdx.x >> 5;
  #pragma unroll
  for (int p = 0; p < 4; ++p)
    t[ri + p * 8][ci] = src[(long)(bt * 32 + ri + p * 8) * 320 + ft * 32 + ci];
  __syncthreads();
  #pragma unroll
  for (int p = 0; p < 4; ++p) {
    int f = ft * 32 + ri + p * 8;
    if (f < 257) dst[(long)f * B_TOTAL + bt * 32 + ci] = t[ci][ri + p * 8];
  }
}

// ---------------- GEMM: C[B,M] = A[B,K] @ W[M,K]^T (+bias, act) ----------------
// 128x64 tile, 512 threads (8 waves of 32x32), BK=64, dbuf, fully-unrolled K,
// swizzled LDS. ACT: 0 none, 1 relu, 2 sigmoid. OUTF32: fp32 C (scalar stores).
template <int ACT, int OUTF32, int K, int M>
__global__ __launch_bounds__(512, 6) void gemm_tn(const _Float16* __restrict__ A,
                                                  const _Float16* __restrict__ W,
                                                  const float* __restrict__ bias,
                                                  void* __restrict__ C) {
  constexpr int KT = K / 64;
  __shared__ __align__(16) _Float16 As2[2][128 * 64];
  __shared__ __align__(16) _Float16 Ws2[2][64 * 64];
  const int tid = threadIdx.x;
  const int l = tid & 63;
  const int w = tid >> 6;
  int bt, mt;
  swz_bt_mt(blockIdx.x, bt, mt);
  const int wr = w >> 1, wc = w & 1;
  const int sc = ((l & 7) ^ (l >> 3)) * 8;  // pre-swizzled source chunk (elems)
  const int srow = tid >> 3;                // 0..63

  const _Float16* ag = A + (long)(bt * 128 + srow) * K + sc;
  const _Float16* wg = W + (long)(mt * 64 + srow) * K + sc;

  f4 acc[2][2];
  #pragma unroll
  for (int i = 0; i < 2; ++i)
    #pragma unroll
    for (int jj = 0; jj < 2; ++jj) acc[i][jj] = (f4){0.f, 0.f, 0.f, 0.f};

  const int lg = l >> 4;
  const int arow = wr * 32 + (l & 15);
  const int wrow = wc * 32 + (l & 15);

  auto stage = [&](int b, int t) {
    GLL(ag + t * 64, (char*)As2[b] + w * 1024);
    GLL(ag + t * 64 + (long)64 * K, (char*)As2[b] + w * 1024 + 8192);
    GLL(wg + t * 64, (char*)Ws2[b] + w * 1024);
  };

  stage(0, 0);
  __syncthreads();
  #pragma unroll
  for (int i = 0; i < KT; ++i) {
    if (i + 1 < KT) stage((i + 1) & 1, i + 1);
    const h8* AsV = (const h8*)As2[i & 1];
    const h8* WsV = (const h8*)Ws2[i & 1];
    h8 b00 = WsV[swzg(wrow, lg)],      b01 = WsV[swzg(wrow, 4 | lg)];
    h8 b10 = WsV[swzg(wrow + 16, lg)], b11 = WsV[swzg(wrow + 16, 4 | lg)];
    #pragma unroll
    for (int fm = 0; fm < 2; ++fm) {
      h8 a0 = AsV[swzg(arow + fm * 16, lg)];
      h8 a1 = AsV[swzg(arow + fm * 16, 4 | lg)];
      MFMA(acc[fm][0], a0, b00); MFMA(acc[fm][0], a1, b01);
      MFMA(acc[fm][1], a0, b10); MFMA(acc[fm][1], a1, b11);
    }
    __syncthreads();
  }

  const int jloc = wc * 32 + (l & 15);
  const int colBase = mt * 64 + jloc;
  if (OUTF32) {
    const int rowBase = bt * 128 + wr * 32 + (l >> 4) * 4;
    #pragma unroll
    for (int fn = 0; fn < 2; ++fn) {
      const float bb = bias[colBase + fn * 16];
      #pragma unroll
      for (int fm = 0; fm < 2; ++fm)
        #pragma unroll
        for (int r = 0; r < 4; ++r) {
          float x = acc[fm][fn][r] + bb;
          if (ACT == 2) x = 1.f / (1.f + __expf(-x));
          ((float*)C)[(long)(rowBase + fm * 16 + r) * M + colBase + fn * 16] = x;
        }
    }
  } else {
    // LDS-transpose epilogue: frags -> [128][72] fp16 -> dense 16B stores
    _Float16* scr = (_Float16*)As2;
    const int rowLoc = wr * 32 + (l >> 4) * 4;
    #pragma unroll
    for (int fn = 0; fn < 2; ++fn) {
      const float bb = bias[colBase + fn * 16];
      #pragma unroll
      for (int fm = 0; fm < 2; ++fm)
        #pragma unroll
        for (int r = 0; r < 4; ++r) {
          float x = acc[fm][fn][r] + bb;
          if (ACT == 1) x = fmaxf(x, 0.f);
          scr[(rowLoc + fm * 16 + r) * 72 + jloc + fn * 16] = (_Float16)x;
        }
    }
    __syncthreads();
    const int rrow = tid >> 2, rq = tid & 3;
    h8 v0 = *(const h8*)(scr + rrow * 72 + rq * 16);
    h8 v1 = *(const h8*)(scr + rrow * 72 + rq * 16 + 8);
    _Float16* gp = (_Float16*)C + (long)(bt * 128 + rrow) * M + mt * 64 + rq * 16;
    *(h8*)gp = v0;
    *(h8*)(gp + 8) = v1;
  }
}

// ---------------- fully-fused GRU layer (4 acc groups, 8 waves) ----------------
// gates = Wi@[x] + Wh@[h], K-concat (steps 0..6 x-tiles, 7..13 h-tiles rotated
// to end at h-tile mt -> h_old in As2[1] for the blend). acc: z, r, nx, nh.
__global__ __launch_bounds__(512, 4) void gemm_gru(const _Float16* __restrict__ Ax,
                                                   const _Float16* __restrict__ Ah,
                                                   const _Float16* __restrict__ Wi_,
                                                   const _Float16* __restrict__ Wh_,
                                                   const float* __restrict__ bi,
                                                   const float* __restrict__ bh,
                                                   _Float16* __restrict__ Hn) {
  __shared__ __align__(16) _Float16 As2[2][128 * 64];
  __shared__ __align__(16) _Float16 Ws2[2][3][64 * 64];
  const int tid = threadIdx.x;
  const int l = tid & 63;
  const int w = tid >> 6;
  int bt, mt;
  swz_bt_mt(blockIdx.x, bt, mt);  // mt in [0,7)
  const int wr = w >> 1, wc = w & 1;
  const int sc = ((l & 7) ^ (l >> 3)) * 8;
  const int srow = tid >> 3;

  const long arowg = (long)(bt * 128 + srow) * 448 + sc;
  const long wrowg = (long)(mt * 64 + srow) * 448 + sc;

  f4 acc[4][2][2];
  #pragma unroll
  for (int g = 0; g < 4; ++g)
    #pragma unroll
    for (int i = 0; i < 2; ++i)
      #pragma unroll
      for (int jj = 0; jj < 2; ++jj) acc[g][i][jj] = (f4){0.f, 0.f, 0.f, 0.f};

  const int lg = l >> 4;
  const int arow = wr * 32 + (l & 15);
  const int wrow = wc * 32 + (l & 15);

  // step i: i<7 -> x-tile i; i>=7 -> h-tile (mt+i-6)%7; last (i=13) = h-tile mt.
  auto stage = [&](int b, int i) {
    const _Float16* ab = (i >= 7) ? Ah : Ax;
    const _Float16* wb = (i >= 7) ? Wh_ : Wi_;
    const int kc = ((i >= 7) ? (mt + i - 6) % 7 : i) * 64;
    GLL(ab + arowg + kc, (char*)As2[b] + w * 1024);
    GLL(ab + arowg + kc + 64 * 448, (char*)As2[b] + w * 1024 + 8192);
    #pragma unroll
    for (int g = 0; g < 3; ++g)
      GLL(wb + wrowg + (long)g * 200704 + kc, (char*)Ws2[b][g] + w * 1024);
  };

  stage(0, 0);
  __syncthreads();
  #pragma unroll
  for (int i = 0; i < 14; ++i) {
    if (i < 13) stage((i + 1) & 1, i + 1);
    const h8* AsV = (const h8*)As2[i & 1];
    const h8* WsV = (const h8*)Ws2[i & 1][0];
    h8 a00 = AsV[swzg(arow, lg)],      a01 = AsV[swzg(arow, 4 | lg)];
    h8 a10 = AsV[swzg(arow + 16, lg)], a11 = AsV[swzg(arow + 16, 4 | lg)];
    #pragma unroll
    for (int g = 0; g < 3; ++g) {
      const int d = (g == 2) ? ((i < 7) ? 2 : 3) : g;  // folds after unroll
      h8 b00 = WsV[g * 512 + swzg(wrow, lg)];
      h8 b01 = WsV[g * 512 + swzg(wrow, 4 | lg)];
      h8 b10 = WsV[g * 512 + swzg(wrow + 16, lg)];
      h8 b11 = WsV[g * 512 + swzg(wrow + 16, 4 | lg)];
      MFMA(acc[d][0][0], a00, b00); MFMA(acc[d][0][0], a01, b01);
      MFMA(acc[d][0][1], a00, b10); MFMA(acc[d][0][1], a01, b11);
      MFMA(acc[d][1][0], a10, b00); MFMA(acc[d][1][0], a11, b01);
      MFMA(acc[d][1][1], a10, b10); MFMA(acc[d][1][1], a11, b11);
    }
    __syncthreads();
  }

  // epilogue: gate math; h_old from As2[1] (h-tile mt); Hn via Ws2 scratch
  const _Float16* Alast = As2[1];
  _Float16* scr = (_Float16*)Ws2;  // [128][72] fp16 = 18.4 KB
  const int jloc = wc * 32 + (l & 15);
  const int rowLoc = wr * 32 + (l >> 4) * 4;
  #pragma unroll
  for (int fn = 0; fn < 2; ++fn) {
    const int j = mt * 64 + jloc + fn * 16;
    const float bz = bi[j] + bh[j];
    const float br = bi[448 + j] + bh[448 + j];
    const float bnx = bi[896 + j], bnh = bh[896 + j];
    #pragma unroll
    for (int fm = 0; fm < 2; ++fm) {
      #pragma unroll
      for (int r = 0; r < 4; ++r) {
        const float zz = 1.f / (1.f + __expf(-(acc[0][fm][fn][r] + bz)));
        const float rr = 1.f / (1.f + __expf(-(acc[1][fm][fn][r] + br)));
        const float nn = (acc[2][fm][fn][r] + bnx) + rr * (acc[3][fm][fn][r] + bnh);
        const float th = 1.f - 2.f / (__expf(2.f * nn) + 1.f);  // tanh
        const int row = rowLoc + fm * 16 + r;
        const int col = jloc + fn * 16;
        const float ho = (float)Alast[swzg(row, col >> 3) * 8 + (col & 7)];
        scr[row * 72 + col] = (_Float16)((1.f - zz) * th + zz * ho);
      }
    }
  }
  __syncthreads();
  const int rrow = tid >> 2, rq = tid & 3;
  h8 v0 = *(const h8*)(scr + rrow * 72 + rq * 16);
  h8 v1 = *(const h8*)(scr + rrow * 72 + rq * 16 + 8);
  _Float16* gp = Hn + (long)(bt * 128 + rrow) * 448 + mt * 64 + rq * 16;
  *(h8*)gp = v0;
  *(h8*)(gp + 8) = v1;
}

// ---------------- launch ----------------
extern "C" void kernel_launch(void* const* d_in, const int* in_sizes, int n_in,
                              void* d_out, int out_size, void* d_ws, size_t ws_size,
                              hipStream_t stream) {
  char* ws = (char*)d_ws;
  _Float16* W16  = (_Float16*)(ws);                 // 3,452,928 fp16
  float*    BIAS = (float*)(ws + 6905856L);         // 7,424 f32
  _Float16* buf2 = (_Float16*)(ws + 6935552L);      // xT [B,320] -> y1 [B,640] -> outT f32 [B,320]
  _Float16* buf3 = (_Float16*)(ws + 27907072L);     // fc1out [B,448] -> y2 [B,640]
  _Float16* buf4 = (_Float16*)(ws + 48878592L);     // h1_old -> h2_new [B,448]
  _Float16* buf5 = (_Float16*)(ws + 63558656L);     // h2_old [B,448]
  _Float16* buf6 = (_Float16*)(ws + 78238720L);     // h1_new [B,448]
  float* outT = (float*)buf2;                       // [B,320] f32 (y1 dead by fc4)
  if (ws_size < 92918784UL) return;  // loud failure rather than OOB

  SrcPtrs sp;
  for (int i = 0; i < 35; ++i) sp.p[i] = (const float*)d_in[i];

  prep_weights<<<dim3(13517), dim3(256), 0, stream>>>(sp, W16, BIAS);
  transpose_in<<<dim3(19456), dim3(256), 0, stream>>>((const float*)d_in[0], (const float*)d_in[1],
                                                      (const float*)d_in[2], buf2, buf4, buf5);

  // fc1: [B,320] @ [448,320]^T -> [B,448]
  gemm_tn<0, 0, 320, 448><<<dim3(128 * 7), dim3(512), 0, stream>>>(buf2, W16, BIAS, (void*)buf3);
  // GRU1 (fused): gates from [fc1out ; h1_old], writes h1_new
  gemm_gru<<<dim3(128 * 7), dim3(512), 0, stream>>>(buf3, buf4, W16 + 143360, W16 + 745472,
                                                    BIAS + 448, BIAS + 1792, buf6);
  // GRU2 (fused): gates from [h1_new ; h2_old], writes h2_new
  gemm_gru<<<dim3(128 * 7), dim3(512), 0, stream>>>(buf6, buf5, W16 + 1347584, W16 + 1949696,
                                                    BIAS + 3136, BIAS + 4480, buf4);
  // fc2 (relu), fc3 (relu), fc4 (sigmoid, fp32 out)
  gemm_tn<1, 0, 448, 640><<<dim3(128 * 10), dim3(512), 0, stream>>>(buf4, W16 + 2551808, BIAS + 5824, (void*)buf2);
  gemm_tn<1, 0, 640, 640><<<dim3(128 * 10), dim3(512), 0, stream>>>(buf2, W16 + 2838528, BIAS + 6464, (void*)buf3);
  gemm_tn<2, 1, 640, 320><<<dim3(128 * 5), dim3(512), 0, stream>>>(buf3, W16 + 3248128, BIAS + 7104, (void*)outT);

  transpose_out<<<dim3(10 * 512), dim3(256), 0, stream>>>(outT, (float*)d_out);
}